// Round 1
// baseline (3264.641 us; speedup 1.0000x reference)
//
#include <hip/hip_runtime.h>
#include <math.h>

#define B_ROWS 16384
#define D_DIM  2048
#define H_DIM  512

// ---------------- Kernel 1: predictor GEMM, fp64 accumulation ----------------
// h = relu(x @ W1 + b1); logit_partial[row] += sum_j h[row,j] * W2[j]
// Tile: BM=64 rows x BN=128 cols, BK=16. 256 threads, micro-tile 4x8 per thread.
#define BM 64
#define BN 128
#define BK 16

__global__ __launch_bounds__(256) void predictor_gemm(
    const float* __restrict__ x, const float* __restrict__ W1,
    const float* __restrict__ b1, const float* __restrict__ W2,
    double* __restrict__ logit)
{
    __shared__ double xs[BK][BM];        // 8 KB   (k-major, [kk][row])
    __shared__ double wsh[BK][BN + 2];   // ~16.3 KB
    __shared__ double red[BM][17];       // 8.5 KB (row-reduction buffer)

    const int tid = threadIdx.x;
    const int tx = tid & 15;             // col group: 8 cols each -> 128
    const int ty = tid >> 4;             // row group: 4 rows each -> 64
    const int rowBase = blockIdx.x * BM;
    const int jBase   = blockIdx.y * BN;

    double acc[4][8];
    #pragma unroll
    for (int r = 0; r < 4; ++r)
        #pragma unroll
        for (int c = 0; c < 8; ++c) acc[r][c] = 0.0;

    const int xr = tid >> 2;             // 0..63
    const int xk = (tid & 3) * 4;        // 0,4,8,12
    const int wk = tid >> 4;             // 0..15
    const int wj = (tid & 15) * 8;       // 0..120

    for (int k0 = 0; k0 < D_DIM; k0 += BK) {
        // stage x tile 64x16 (fp32 -> fp64)
        float4 xv  = *(const float4*)(x  + (size_t)(rowBase + xr) * D_DIM + k0 + xk);
        // stage W1 tile 16x128
        float4 wv0 = *(const float4*)(W1 + (size_t)(k0 + wk) * H_DIM + jBase + wj);
        float4 wv1 = *(const float4*)(W1 + (size_t)(k0 + wk) * H_DIM + jBase + wj + 4);

        xs[xk + 0][xr] = (double)xv.x;
        xs[xk + 1][xr] = (double)xv.y;
        xs[xk + 2][xr] = (double)xv.z;
        xs[xk + 3][xr] = (double)xv.w;
        wsh[wk][wj + 0] = (double)wv0.x;
        wsh[wk][wj + 1] = (double)wv0.y;
        wsh[wk][wj + 2] = (double)wv0.z;
        wsh[wk][wj + 3] = (double)wv0.w;
        wsh[wk][wj + 4] = (double)wv1.x;
        wsh[wk][wj + 5] = (double)wv1.y;
        wsh[wk][wj + 6] = (double)wv1.z;
        wsh[wk][wj + 7] = (double)wv1.w;
        __syncthreads();

        #pragma unroll
        for (int kk = 0; kk < BK; ++kk) {
            double a[4], b[8];
            #pragma unroll
            for (int r = 0; r < 4; ++r) a[r] = xs[kk][ty * 4 + r];
            #pragma unroll
            for (int c = 0; c < 8; ++c) b[c] = wsh[kk][tx * 8 + c];
            #pragma unroll
            for (int r = 0; r < 4; ++r)
                #pragma unroll
                for (int c = 0; c < 8; ++c)
                    acc[r][c] = fma(a[r], b[c], acc[r][c]);
        }
        __syncthreads();
    }

    // epilogue: + b1, relu, dot with W2 -> per-row partial
    double p[4] = {0.0, 0.0, 0.0, 0.0};
    #pragma unroll
    for (int c = 0; c < 8; ++c) {
        const int j = jBase + tx * 8 + c;
        const double bb = (double)b1[j];
        const double w2 = (double)W2[j];
        #pragma unroll
        for (int r = 0; r < 4; ++r) {
            double h = acc[r][c] + bb;
            if (h > 0.0) p[r] = fma(h, w2, p[r]);
        }
    }
    #pragma unroll
    for (int r = 0; r < 4; ++r) red[ty * 4 + r][tx] = p[r];
    __syncthreads();
    if (tid < BM) {
        double s = 0.0;
        #pragma unroll
        for (int t = 0; t < 16; ++t) s += red[tid][t];
        atomicAdd(&logit[rowBase + tid], s);   // 4 j-blocks contribute per row
    }
}

// ------------- Kernel 2: per-row radix-select threshold + writeback -------------
__global__ __launch_bounds__(256) void select_and_write(
    const float* __restrict__ x, const float* __restrict__ b2,
    const double* __restrict__ logit,
    float* __restrict__ out_sparse, float* __restrict__ out_mask,
    float* __restrict__ out_sparsity, float* __restrict__ out_actual,
    double* __restrict__ l1rows)
{
    __shared__ int    hist[256];
    __shared__ int    sh_k;
    __shared__ int    sh_digit;
    __shared__ int    sh_krem;
    __shared__ double wsum[4];
    __shared__ int    wcnt[4];

    const int row = blockIdx.x;
    const int tid = threadIdx.x;
    const float4* xr4 = (const float4*)(x + (size_t)row * D_DIM);

    const float4 va = xr4[tid];
    const float4 vb = xr4[tid + 256];
    float v[8] = {va.x, va.y, va.z, va.w, vb.x, vb.y, vb.z, vb.w};
    unsigned u[8];
    #pragma unroll
    for (int i = 0; i < 8; ++i) u[i] = __float_as_uint(v[i]) & 0x7FFFFFFFu;

    if (tid == 0) {
        // fp64 sigmoid -> sparsity -> k (half-even rounding, matches np.round)
        double L = logit[row] + (double)b2[0];
        double sig = 1.0 / (1.0 + exp(-L));
        double s = 0.05 + 0.25 * sig;              // MIN_S + (MAX_S-MIN_S)*sig
        int k = (int)rint(2048.0 * (1.0 - s));
        if (k < 1) k = 1;
        if (k > 2048) k = 2048;
        sh_k = k;
        out_sparsity[row] = (float)s;
    }
    __syncthreads();

    int krem = sh_k;            // rank (1-indexed) of k-th SMALLEST |x|
    unsigned prefix = 0;

    // 4-pass MSD radix select on abs-bit pattern (monotone for non-negative floats)
    for (int shift = 24; shift >= 0; shift -= 8) {
        const unsigned pmask = (shift == 24) ? 0u : (0xFFFFFFFFu << (shift + 8));
        hist[tid] = 0;
        __syncthreads();
        #pragma unroll
        for (int i = 0; i < 8; ++i)
            if ((u[i] & pmask) == prefix)
                atomicAdd(&hist[(u[i] >> shift) & 255], 1);
        __syncthreads();
        if (tid < 64) {
            const int b0 = hist[4 * tid + 0];
            const int b1_ = hist[4 * tid + 1];
            const int b2_ = hist[4 * tid + 2];
            const int b3_ = hist[4 * tid + 3];
            const int tot = b0 + b1_ + b2_ + b3_;
            int sc = tot;
            #pragma unroll
            for (int off = 1; off < 64; off <<= 1) {
                int n = __shfl_up(sc, off);
                if (tid >= off) sc += n;
            }
            const int excl = sc - tot;        // count of elems in bins < 4*tid
            const int c0 = excl, c1 = c0 + b0, c2 = c1 + b1_, c3 = c2 + b2_;
            int d = -1, cb = 0;
            if      (krem > c0 && krem <= c1)        { d = 4 * tid + 0; cb = c0; }
            else if (krem > c1 && krem <= c2)        { d = 4 * tid + 1; cb = c1; }
            else if (krem > c2 && krem <= c3)        { d = 4 * tid + 2; cb = c2; }
            else if (krem > c3 && krem <= c3 + b3_)  { d = 4 * tid + 3; cb = c3; }
            if (d >= 0) { sh_digit = d; sh_krem = krem - cb; }  // exactly one lane
        }
        __syncthreads();
        prefix |= ((unsigned)sh_digit) << shift;
        krem = sh_krem;
        // safe: next writes to sh_digit/sh_krem are two barriers away
    }
    const unsigned thr = prefix;  // exact bit pattern of k-th smallest |x|

    // writeback: mask = (|x| > thr) bitwise-identical to reference float compare
    float m[8];
    int cnt = 0;
    double lp = 0.0;
    #pragma unroll
    for (int i = 0; i < 8; ++i) {
        const bool keep = (u[i] > thr);
        m[i] = keep ? 1.0f : 0.0f;
        cnt += keep ? 1 : 0;
        if (keep) lp += (double)fabsf(v[i]);
    }
    float4* os4 = (float4*)(out_sparse + (size_t)row * D_DIM);
    float4* om4 = (float4*)(out_mask   + (size_t)row * D_DIM);
    float4 s0 = {m[0] != 0.0f ? v[0] : 0.0f, m[1] != 0.0f ? v[1] : 0.0f,
                 m[2] != 0.0f ? v[2] : 0.0f, m[3] != 0.0f ? v[3] : 0.0f};
    float4 s1 = {m[4] != 0.0f ? v[4] : 0.0f, m[5] != 0.0f ? v[5] : 0.0f,
                 m[6] != 0.0f ? v[6] : 0.0f, m[7] != 0.0f ? v[7] : 0.0f};
    float4 m0 = {m[0], m[1], m[2], m[3]};
    float4 m1 = {m[4], m[5], m[6], m[7]};
    os4[tid]       = s0;
    os4[tid + 256] = s1;
    om4[tid]       = m0;
    om4[tid + 256] = m1;

    // per-row reductions (count, L1)
    #pragma unroll
    for (int off = 32; off > 0; off >>= 1) {
        lp  += __shfl_down(lp, off);
        cnt += __shfl_down(cnt, off);
    }
    const int wave = tid >> 6, lane = tid & 63;
    if (lane == 0) { wsum[wave] = lp; wcnt[wave] = cnt; }
    __syncthreads();
    if (tid == 0) {
        const double t = wsum[0] + wsum[1] + wsum[2] + wsum[3];
        const int    c = wcnt[0] + wcnt[1] + wcnt[2] + wcnt[3];
        l1rows[row] = t;
        out_actual[row] = (float)c * (1.0f / 2048.0f);  // exact: /2^11
    }
}

// ---------------- Kernel 3: reduce row L1 sums -> l1_reg ----------------
__global__ __launch_bounds__(256) void finalize_l1(
    const double* __restrict__ l1rows, float* __restrict__ out_l1)
{
    __shared__ double sh[256];
    double s = 0.0;
    for (int i = threadIdx.x; i < B_ROWS; i += 256) s += l1rows[i];
    sh[threadIdx.x] = s;
    __syncthreads();
    for (int st = 128; st > 0; st >>= 1) {
        if (threadIdx.x < st) sh[threadIdx.x] += sh[threadIdx.x + st];
        __syncthreads();
    }
    if (threadIdx.x == 0) out_l1[0] = (float)(sh[0] / (double)B_ROWS);
}

extern "C" void kernel_launch(void* const* d_in, const int* in_sizes, int n_in,
                              void* d_out, int out_size, void* d_ws, size_t ws_size,
                              hipStream_t stream) {
    const float* x  = (const float*)d_in[0];
    const float* W1 = (const float*)d_in[1];
    const float* b1 = (const float*)d_in[2];
    const float* W2 = (const float*)d_in[3];
    const float* b2 = (const float*)d_in[4];

    float* out = (float*)d_out;
    float* out_sparse   = out;                                   // B*D
    float* out_mask     = out + (size_t)B_ROWS * D_DIM;          // B*D
    float* out_sparsity = out + 2ull * B_ROWS * D_DIM;           // B
    float* out_actual   = out_sparsity + B_ROWS;                 // B
    float* out_l1       = out_actual + B_ROWS;                   // 1

    double* logit  = (double*)d_ws;        // B doubles (atomically accumulated)
    double* l1rows = logit + B_ROWS;       // B doubles (written, no init needed)

    hipMemsetAsync(d_ws, 0, (size_t)B_ROWS * sizeof(double), stream);

    dim3 g1(B_ROWS / BM, H_DIM / BN);
    predictor_gemm<<<g1, 256, 0, stream>>>(x, W1, b1, W2, logit);
    select_and_write<<<B_ROWS, 256, 0, stream>>>(x, b2, logit, out_sparse, out_mask,
                                                 out_sparsity, out_actual, l1rows);
    finalize_l1<<<1, 256, 0, stream>>>(l1rows, out_l1);
}

// Round 2
// 863.745 us; speedup vs baseline: 3.7796x; 3.7796x over previous
//
#include <hip/hip_runtime.h>
#include <math.h>

#define B_ROWS 16384
#define D_DIM  2048
#define H_DIM  512

// ---------------- Kernel 1: predictor GEMM, fp32 products + fp64 epilogue ----------------
// h = relu(x @ W1 + b1); logit[row] += sum_j h[row,j] * W2[j]  (fp64 reduce)
// BM=64 rows x BN=256 cols, BK=16, 256 threads, micro-tile 16x4.
#define BM 64
#define BN 256
#define BK 16

__global__ __launch_bounds__(256, 2) void predictor_gemm(
    const float* __restrict__ x, const float* __restrict__ W1,
    const float* __restrict__ b1, const float* __restrict__ W2,
    double* __restrict__ logit)
{
    __shared__ float xs[2][BK][BM];    // 2 x 4 KB, k-major (transposed on store)
    __shared__ float wsh[2][BK][BN];   // 2 x 16 KB, row-major

    const int tid = threadIdx.x;
    const int tx = tid & 63;             // col group: 4 cols each -> 256
    const int ty = tid >> 6;             // row group: 16 rows each -> 64 (== wave id)
    const int rowBase = blockIdx.x * BM;
    const int jBase   = blockIdx.y * BN;

    // staging thread roles
    const int xr = tid & 63;             // x: row within tile
    const int xk = (tid >> 6) * 4;       // x: k offset (0,4,8,12)
    const int wk = tid >> 4;             // W: k row 0..15
    const int wj = (tid & 15) * 4;       // W: col offset 0..60 (chunks of 64 apart)

    float acc[16][4];
    #pragma unroll
    for (int r = 0; r < 16; ++r)
        #pragma unroll
        for (int c = 0; c < 4; ++c) acc[r][c] = 0.0f;

    // prefetch tile 0
    float4 xv = *(const float4*)(x + (size_t)(rowBase + xr) * D_DIM + xk);
    float4 wv[4];
    #pragma unroll
    for (int c = 0; c < 4; ++c)
        wv[c] = *(const float4*)(W1 + (size_t)wk * H_DIM + jBase + wj + 64 * c);

    int cur = 0;
    // store tile 0
    xs[0][xk + 0][xr] = xv.x;
    xs[0][xk + 1][xr] = xv.y;
    xs[0][xk + 2][xr] = xv.z;
    xs[0][xk + 3][xr] = xv.w;
    #pragma unroll
    for (int c = 0; c < 4; ++c)
        *(float4*)&wsh[0][wk][wj + 64 * c] = wv[c];
    __syncthreads();

    for (int k0 = 0; k0 < D_DIM; k0 += BK) {
        const bool has_next = (k0 + BK) < D_DIM;
        if (has_next) {
            xv = *(const float4*)(x + (size_t)(rowBase + xr) * D_DIM + (k0 + BK) + xk);
            #pragma unroll
            for (int c = 0; c < 4; ++c)
                wv[c] = *(const float4*)(W1 + (size_t)(k0 + BK + wk) * H_DIM + jBase + wj + 64 * c);
        }

        #pragma unroll
        for (int kk = 0; kk < BK; ++kk) {
            const float4 b4 = *(const float4*)&wsh[cur][kk][tx * 4];
            float4 a4[4];
            #pragma unroll
            for (int i = 0; i < 4; ++i)
                a4[i] = *(const float4*)&xs[cur][kk][ty * 16 + 4 * i];
            const float a_[16] = {a4[0].x, a4[0].y, a4[0].z, a4[0].w,
                                  a4[1].x, a4[1].y, a4[1].z, a4[1].w,
                                  a4[2].x, a4[2].y, a4[2].z, a4[2].w,
                                  a4[3].x, a4[3].y, a4[3].z, a4[3].w};
            const float b_[4] = {b4.x, b4.y, b4.z, b4.w};
            #pragma unroll
            for (int r = 0; r < 16; ++r)
                #pragma unroll
                for (int c = 0; c < 4; ++c)
                    acc[r][c] = fmaf(a_[r], b_[c], acc[r][c]);
        }

        if (has_next) {
            const int nxt = cur ^ 1;
            xs[nxt][xk + 0][xr] = xv.x;
            xs[nxt][xk + 1][xr] = xv.y;
            xs[nxt][xk + 2][xr] = xv.z;
            xs[nxt][xk + 3][xr] = xv.w;
            #pragma unroll
            for (int c = 0; c < 4; ++c)
                *(float4*)&wsh[nxt][wk][wj + 64 * c] = wv[c];
            __syncthreads();
            cur = nxt;
        }
    }

    // epilogue: +b1, relu, fp64 dot with W2, wave-reduce (wave == 16 complete rows)
    double p[16];
    #pragma unroll
    for (int r = 0; r < 16; ++r) p[r] = 0.0;
    #pragma unroll
    for (int c = 0; c < 4; ++c) {
        const int j = jBase + tx * 4 + c;
        const float bb = b1[j];
        const double w2 = (double)W2[j];
        #pragma unroll
        for (int r = 0; r < 16; ++r) {
            const float h = acc[r][c] + bb;
            if (h > 0.0f) p[r] = fma((double)h, w2, p[r]);
        }
    }
    #pragma unroll
    for (int r = 0; r < 16; ++r) {
        double v = p[r];
        #pragma unroll
        for (int off = 32; off > 0; off >>= 1)
            v += __shfl_down(v, off);
        if (tx == 0) atomicAdd(&logit[rowBase + ty * 16 + r], v);
    }
}

// ------------- Kernel 2: per-row radix-select threshold + writeback -------------
__global__ __launch_bounds__(256) void select_and_write(
    const float* __restrict__ x, const float* __restrict__ b2,
    const double* __restrict__ logit,
    float* __restrict__ out_sparse, float* __restrict__ out_mask,
    float* __restrict__ out_sparsity, float* __restrict__ out_actual,
    double* __restrict__ l1rows)
{
    __shared__ int    hist[256];
    __shared__ int    sh_k;
    __shared__ int    sh_digit;
    __shared__ int    sh_krem;
    __shared__ double wsum[4];
    __shared__ int    wcnt[4];

    const int row = blockIdx.x;
    const int tid = threadIdx.x;
    const float4* xr4 = (const float4*)(x + (size_t)row * D_DIM);

    const float4 va = xr4[tid];
    const float4 vb = xr4[tid + 256];
    float v[8] = {va.x, va.y, va.z, va.w, vb.x, vb.y, vb.z, vb.w};
    unsigned u[8];
    #pragma unroll
    for (int i = 0; i < 8; ++i) u[i] = __float_as_uint(v[i]) & 0x7FFFFFFFu;

    if (tid == 0) {
        double L = logit[row] + (double)b2[0];
        double sig = 1.0 / (1.0 + exp(-L));
        double s = 0.05 + 0.25 * sig;              // MIN_S + (MAX_S-MIN_S)*sig
        int k = (int)rint(2048.0 * (1.0 - s));     // half-even, matches np.round
        if (k < 1) k = 1;
        if (k > 2048) k = 2048;
        sh_k = k;
        out_sparsity[row] = (float)s;
    }
    __syncthreads();

    int krem = sh_k;            // rank (1-indexed) of k-th SMALLEST |x|
    unsigned prefix = 0;

    // 4-pass MSD radix select on abs-bit pattern (monotone for non-negative floats)
    for (int shift = 24; shift >= 0; shift -= 8) {
        const unsigned pmask = (shift == 24) ? 0u : (0xFFFFFFFFu << (shift + 8));
        hist[tid] = 0;
        __syncthreads();
        #pragma unroll
        for (int i = 0; i < 8; ++i)
            if ((u[i] & pmask) == prefix)
                atomicAdd(&hist[(u[i] >> shift) & 255], 1);
        __syncthreads();
        if (tid < 64) {
            const int b0 = hist[4 * tid + 0];
            const int b1_ = hist[4 * tid + 1];
            const int b2_ = hist[4 * tid + 2];
            const int b3_ = hist[4 * tid + 3];
            const int tot = b0 + b1_ + b2_ + b3_;
            int sc = tot;
            #pragma unroll
            for (int off = 1; off < 64; off <<= 1) {
                int n = __shfl_up(sc, off);
                if (tid >= off) sc += n;
            }
            const int excl = sc - tot;        // elems in bins < 4*tid
            const int c0 = excl, c1 = c0 + b0, c2 = c1 + b1_, c3 = c2 + b2_;
            int d = -1, cb = 0;
            if      (krem > c0 && krem <= c1)        { d = 4 * tid + 0; cb = c0; }
            else if (krem > c1 && krem <= c2)        { d = 4 * tid + 1; cb = c1; }
            else if (krem > c2 && krem <= c3)        { d = 4 * tid + 2; cb = c2; }
            else if (krem > c3 && krem <= c3 + b3_)  { d = 4 * tid + 3; cb = c3; }
            if (d >= 0) { sh_digit = d; sh_krem = krem - cb; }  // exactly one lane
        }
        __syncthreads();
        prefix |= ((unsigned)sh_digit) << shift;
        krem = sh_krem;
    }
    const unsigned thr = prefix;  // exact bit pattern of k-th smallest |x|

    // writeback: mask = (|x| > thr), bitwise-identical to reference float compare
    float m[8];
    int cnt = 0;
    double lp = 0.0;
    #pragma unroll
    for (int i = 0; i < 8; ++i) {
        const bool keep = (u[i] > thr);
        m[i] = keep ? 1.0f : 0.0f;
        cnt += keep ? 1 : 0;
        if (keep) lp += (double)fabsf(v[i]);
    }
    float4* os4 = (float4*)(out_sparse + (size_t)row * D_DIM);
    float4* om4 = (float4*)(out_mask   + (size_t)row * D_DIM);
    float4 s0 = {m[0] != 0.0f ? v[0] : 0.0f, m[1] != 0.0f ? v[1] : 0.0f,
                 m[2] != 0.0f ? v[2] : 0.0f, m[3] != 0.0f ? v[3] : 0.0f};
    float4 s1 = {m[4] != 0.0f ? v[4] : 0.0f, m[5] != 0.0f ? v[5] : 0.0f,
                 m[6] != 0.0f ? v[6] : 0.0f, m[7] != 0.0f ? v[7] : 0.0f};
    float4 m0 = {m[0], m[1], m[2], m[3]};
    float4 m1 = {m[4], m[5], m[6], m[7]};
    os4[tid]       = s0;
    os4[tid + 256] = s1;
    om4[tid]       = m0;
    om4[tid + 256] = m1;

    #pragma unroll
    for (int off = 32; off > 0; off >>= 1) {
        lp  += __shfl_down(lp, off);
        cnt += __shfl_down(cnt, off);
    }
    const int wave = tid >> 6, lane = tid & 63;
    if (lane == 0) { wsum[wave] = lp; wcnt[wave] = cnt; }
    __syncthreads();
    if (tid == 0) {
        const double t = wsum[0] + wsum[1] + wsum[2] + wsum[3];
        const int    c = wcnt[0] + wcnt[1] + wcnt[2] + wcnt[3];
        l1rows[row] = t;
        out_actual[row] = (float)c * (1.0f / 2048.0f);
    }
}

// ---------------- Kernel 3: reduce row L1 sums -> l1_reg ----------------
__global__ __launch_bounds__(256) void finalize_l1(
    const double* __restrict__ l1rows, float* __restrict__ out_l1)
{
    __shared__ double sh[256];
    double s = 0.0;
    for (int i = threadIdx.x; i < B_ROWS; i += 256) s += l1rows[i];
    sh[threadIdx.x] = s;
    __syncthreads();
    for (int st = 128; st > 0; st >>= 1) {
        if (threadIdx.x < st) sh[threadIdx.x] += sh[threadIdx.x + st];
        __syncthreads();
    }
    if (threadIdx.x == 0) out_l1[0] = (float)(sh[0] / (double)B_ROWS);
}

extern "C" void kernel_launch(void* const* d_in, const int* in_sizes, int n_in,
                              void* d_out, int out_size, void* d_ws, size_t ws_size,
                              hipStream_t stream) {
    const float* x  = (const float*)d_in[0];
    const float* W1 = (const float*)d_in[1];
    const float* b1 = (const float*)d_in[2];
    const float* W2 = (const float*)d_in[3];
    const float* b2 = (const float*)d_in[4];

    float* out = (float*)d_out;
    float* out_sparse   = out;                                   // B*D
    float* out_mask     = out + (size_t)B_ROWS * D_DIM;          // B*D
    float* out_sparsity = out + 2ull * B_ROWS * D_DIM;           // B
    float* out_actual   = out_sparsity + B_ROWS;                 // B
    float* out_l1       = out_actual + B_ROWS;                   // 1

    double* logit  = (double*)d_ws;        // B doubles (atomically accumulated)
    double* l1rows = logit + B_ROWS;       // B doubles

    hipMemsetAsync(d_ws, 0, (size_t)B_ROWS * sizeof(double), stream);

    dim3 g1(B_ROWS / BM, H_DIM / BN);
    predictor_gemm<<<g1, 256, 0, stream>>>(x, W1, b1, W2, logit);
    select_and_write<<<B_ROWS, 256, 0, stream>>>(x, b2, logit, out_sparse, out_mask,
                                                 out_sparsity, out_actual, l1rows);
    finalize_l1<<<1, 256, 0, stream>>>(l1rows, out_l1);
}